// Round 21
// baseline (420.225 us; speedup 1.0000x reference)
//
#include <hip/hip_runtime.h>
#include <hip/hip_bf16.h>

#define HDIM 4096
#define EDIM 64
#define ITOK 8          // tokens per wave
#define NW   4          // waves per block (256 threads)
#define BH   64         // h-chunk staged in LDS
#define LDW  (BH + 4)   // 68: row = 272 B -> 16B-aligned b128, optimal banks
#define NCH  (HDIM/BH)  // 64 chunks

typedef float f32x4 __attribute__((ext_vector_type(4)));

// Semantics (locked r16): inputs f32-backed bf16; logit = np-einsum-SSE
// 4-chain f32 mul/add (NO FMA), groups of 8 ascending h, (l0+l1)+(l2+l3),
// bf16-round, f32 routing, f32 out [idx 4T | w 4T | k T].
// r20: aligned b128 LDS reads (stride 68), ITOK=8 halves LDS-read pressure.
__global__ __launch_bounds__(256) void router_lds(
    const float* __restrict__ hidden,
    const float* __restrict__ weight,
    float* __restrict__ out,
    int T)
{
    __shared__ float wlds[2][EDIM][LDW];   // 2 x 17 KB

    const int tid  = threadIdx.x;
    const int lane = tid & 63;
    const int wv   = __builtin_amdgcn_readfirstlane(tid >> 6);
    const int t0   = (blockIdx.x * NW + wv) * ITOK;

    // staging: 256 threads x 16 floats = 64x64 chunk. Row tid>>2, col (tid&3)*16.
    const int srow = tid >> 2;
    const int sq   = (tid & 3) * 16;

    float l[ITOK][4];
#pragma unroll
    for (int i = 0; i < ITOK; ++i)
        { l[i][0]=0.f; l[i][1]=0.f; l[i][2]=0.f; l[i][3]=0.f; }

    // ---- prologue: stage chunk 0 ----
    {
        const float* wp = weight + (size_t)srow * HDIM + sq;
#pragma unroll
        for (int j = 0; j < 16; j += 4)
            *reinterpret_cast<f32x4*>(&wlds[0][srow][sq + j]) =
                *reinterpret_cast<const f32x4*>(wp + j);
    }
    __syncthreads();

    for (int c = 0; c < NCH; ++c) {
        const int cur = c & 1;
        if (c + 1 < NCH) {
            const float* wp = weight + (size_t)srow * HDIM + (c + 1) * BH + sq;
#pragma unroll
            for (int j = 0; j < 16; j += 4)
                *reinterpret_cast<f32x4*>(&wlds[cur ^ 1][srow][sq + j]) =
                    *reinterpret_cast<const f32x4*>(wp + j);
        }

        const int h0 = c * BH;
#pragma unroll
        for (int g = 0; g < BH / 8; ++g) {
            // 16B-aligned b128 reads: addr = (68*lane + 8g)*4, both %16==0
            const f32x4 wa = *reinterpret_cast<const f32x4*>(&wlds[cur][lane][g * 8]);
            const f32x4 wb = *reinterpret_cast<const f32x4*>(&wlds[cur][lane][g * 8 + 4]);
#pragma unroll
            for (int i = 0; i < ITOK; ++i) {
                const float* hp = hidden + (size_t)(t0 + i) * HDIM + h0 + g * 8;
                const f32x4 a0 = *reinterpret_cast<const f32x4*>(hp);
                const f32x4 a1 = *reinterpret_cast<const f32x4*>(hp + 4);
                l[i][0] = __fadd_rn(l[i][0], __fmul_rn(a0.x, wa.x));
                l[i][1] = __fadd_rn(l[i][1], __fmul_rn(a0.y, wa.y));
                l[i][2] = __fadd_rn(l[i][2], __fmul_rn(a0.z, wa.z));
                l[i][3] = __fadd_rn(l[i][3], __fmul_rn(a0.w, wa.w));
                l[i][0] = __fadd_rn(l[i][0], __fmul_rn(a1.x, wb.x));
                l[i][1] = __fadd_rn(l[i][1], __fmul_rn(a1.y, wb.y));
                l[i][2] = __fadd_rn(l[i][2], __fmul_rn(a1.z, wb.z));
                l[i][3] = __fadd_rn(l[i][3], __fmul_rn(a1.w, wb.w));
            }
        }
        __syncthreads();
    }

    const size_t T4 = (size_t)T * 4;

#pragma unroll 1
    for (int i = 0; i < ITOK; ++i) {
        const float acc = __fadd_rn(__fadd_rn(l[i][0], l[i][1]),
                                    __fadd_rn(l[i][2], l[i][3]));
        const float lv = __bfloat162float(__float2bfloat16(acc));

        float mx = lv;
#pragma unroll
        for (int d = 1; d < 64; d <<= 1) mx = fmaxf(mx, __shfl_xor(mx, d));
        const float ev = expf(lv - mx);
        float s = ev;
#pragma unroll
        for (int d = 1; d < 64; d <<= 1) s += __shfl_xor(s, d);
        const float p = ev / s;

        float ent = p * logf(p + 1e-9f);
#pragma unroll
        for (int d = 1; d < 64; d <<= 1) ent += __shfl_xor(ent, d);
        const float Hent = -ent;

        float pv[4]; int pi[4];
        float cand = p;
#pragma unroll
        for (int r = 0; r < 4; ++r) {
            float bv = cand; int bi = lane;
#pragma unroll
            for (int d = 1; d < 64; d <<= 1) {
                float ov = __shfl_xor(bv, d);
                int   oi = __shfl_xor(bi, d);
                if (ov > bv || (ov == bv && oi < bi)) { bv = ov; bi = oi; }
            }
            pv[r] = bv; pi[r] = bi;
            if (lane == bi) cand = -1.f;
        }

        const int kk = (Hent < 0.3f) ? 1 : (Hent > 1.5f) ? 4 : 2;

        float wsum = 0.f;
#pragma unroll
        for (int r = 0; r < 4; ++r) if (r < kk) wsum += pv[r];

        if (lane == 0) {
            const size_t tt = (size_t)(t0 + i);
#pragma unroll
            for (int r = 0; r < 4; ++r) {
                out[tt * 4 + r]      = (r < kk) ? (float)pi[r] : -1.f;
                out[T4 + tt * 4 + r] = (r < kk) ? pv[r] / wsum : 0.f;
            }
            out[2 * T4 + tt] = (float)kk;
        }
    }
}

extern "C" void kernel_launch(void* const* d_in, const int* in_sizes, int n_in,
                              void* d_out, int out_size, void* d_ws, size_t ws_size,
                              hipStream_t stream) {
    const float* hidden = (const float*)d_in[0];
    const float* weight = (const float*)d_in[1];
    float* out = (float*)d_out;
    const int T = in_sizes[0] / HDIM;              // 16384
    const int blocks = T / (NW * ITOK);            // 512
    hipLaunchKernelGGL(router_lds, dim3(blocks), dim3(256), 0, stream,
                       hidden, weight, out, T);
}

// Round 22
// 330.165 us; speedup vs baseline: 1.2728x; 1.2728x over previous
//
#include <hip/hip_runtime.h>
#include <hip/hip_bf16.h>

#define HDIM 4096
#define EDIM 64
#define ITOK 8          // tokens per wave (halves total waves -> halves LDS work)
#define NW   4          // waves per block (256 threads)
#define BH   64         // h-chunk staged in LDS
#define LDW  (BH + 1)   // 65: bank = (lane+c) mod 32, 2-way = free
#define NCH  (HDIM/BH)  // 64 chunks

typedef float f32x4 __attribute__((ext_vector_type(4)));

// Semantics (locked r16): inputs f32-backed bf16; logit = np-einsum-SSE
// 4-chain f32 mul/add (NO FMA), groups of 8 ascending h, (l0+l1)+(l2+l3),
// bf16-round, f32 routing, f32 out [idx 4T | w 4T | k T].
// r22: r19 structure + ITOK=8. Stride-65 LDS (conflict-free), scalar b32 reads.
__global__ __launch_bounds__(256) void router_lds(
    const float* __restrict__ hidden,
    const float* __restrict__ weight,
    float* __restrict__ out,
    int T)
{
    __shared__ float wlds[2][EDIM][LDW];   // 2 x 16.25 KB

    const int tid  = threadIdx.x;
    const int lane = tid & 63;
    const int wv   = __builtin_amdgcn_readfirstlane(tid >> 6);
    const int t0   = (blockIdx.x * NW + wv) * ITOK;

    // staging: 256 threads x 16 floats = 64x64 chunk
    const int srow = tid >> 2;
    const int sq   = (tid & 3) * 16;

    float l[ITOK][4];
#pragma unroll
    for (int i = 0; i < ITOK; ++i)
        { l[i][0]=0.f; l[i][1]=0.f; l[i][2]=0.f; l[i][3]=0.f; }

    // ---- prologue: stage chunk 0 ----
    {
        const float* wp = weight + (size_t)srow * HDIM + sq;
#pragma unroll
        for (int j = 0; j < 16; j += 4) {
            f32x4 v = *reinterpret_cast<const f32x4*>(wp + j);
            wlds[0][srow][sq + j + 0] = v.x;
            wlds[0][srow][sq + j + 1] = v.y;
            wlds[0][srow][sq + j + 2] = v.z;
            wlds[0][srow][sq + j + 3] = v.w;
        }
    }
    __syncthreads();

    for (int c = 0; c < NCH; ++c) {
        const int cur = c & 1;
        if (c + 1 < NCH) {
            const float* wp = weight + (size_t)srow * HDIM + (c + 1) * BH + sq;
#pragma unroll
            for (int j = 0; j < 16; j += 4) {
                f32x4 v = *reinterpret_cast<const f32x4*>(wp + j);
                wlds[cur ^ 1][srow][sq + j + 0] = v.x;
                wlds[cur ^ 1][srow][sq + j + 1] = v.y;
                wlds[cur ^ 1][srow][sq + j + 2] = v.z;
                wlds[cur ^ 1][srow][sq + j + 3] = v.w;
            }
        }

        const int h0 = c * BH;
#pragma unroll
        for (int g = 0; g < BH / 8; ++g) {
            float w0x = wlds[cur][lane][g*8+0], w0y = wlds[cur][lane][g*8+1];
            float w0z = wlds[cur][lane][g*8+2], w0w = wlds[cur][lane][g*8+3];
            float w1x = wlds[cur][lane][g*8+4], w1y = wlds[cur][lane][g*8+5];
            float w1z = wlds[cur][lane][g*8+6], w1w = wlds[cur][lane][g*8+7];
#pragma unroll
            for (int i = 0; i < ITOK; ++i) {
                const float* hp = hidden + (size_t)(t0 + i) * HDIM + h0 + g*8;
                const f32x4 a0 = *reinterpret_cast<const f32x4*>(hp);
                const f32x4 a1 = *reinterpret_cast<const f32x4*>(hp + 4);
                l[i][0] = __fadd_rn(l[i][0], __fmul_rn(a0.x, w0x));
                l[i][1] = __fadd_rn(l[i][1], __fmul_rn(a0.y, w0y));
                l[i][2] = __fadd_rn(l[i][2], __fmul_rn(a0.z, w0z));
                l[i][3] = __fadd_rn(l[i][3], __fmul_rn(a0.w, w0w));
                l[i][0] = __fadd_rn(l[i][0], __fmul_rn(a1.x, w1x));
                l[i][1] = __fadd_rn(l[i][1], __fmul_rn(a1.y, w1y));
                l[i][2] = __fadd_rn(l[i][2], __fmul_rn(a1.z, w1z));
                l[i][3] = __fadd_rn(l[i][3], __fmul_rn(a1.w, w1w));
            }
        }
        __syncthreads();
    }

    const size_t T4 = (size_t)T * 4;

#pragma unroll 1
    for (int i = 0; i < ITOK; ++i) {
        const float acc = __fadd_rn(__fadd_rn(l[i][0], l[i][1]),
                                    __fadd_rn(l[i][2], l[i][3]));
        const float lv = __bfloat162float(__float2bfloat16(acc));

        float mx = lv;
#pragma unroll
        for (int d = 1; d < 64; d <<= 1) mx = fmaxf(mx, __shfl_xor(mx, d));
        const float ev = expf(lv - mx);
        float s = ev;
#pragma unroll
        for (int d = 1; d < 64; d <<= 1) s += __shfl_xor(s, d);
        const float p = ev / s;

        float ent = p * logf(p + 1e-9f);
#pragma unroll
        for (int d = 1; d < 64; d <<= 1) ent += __shfl_xor(ent, d);
        const float Hent = -ent;

        float pv[4]; int pi[4];
        float cand = p;
#pragma unroll
        for (int r = 0; r < 4; ++r) {
            float bv = cand; int bi = lane;
#pragma unroll
            for (int d = 1; d < 64; d <<= 1) {
                float ov = __shfl_xor(bv, d);
                int   oi = __shfl_xor(bi, d);
                if (ov > bv || (ov == bv && oi < bi)) { bv = ov; bi = oi; }
            }
            pv[r] = bv; pi[r] = bi;
            if (lane == bi) cand = -1.f;
        }

        const int kk = (Hent < 0.3f) ? 1 : (Hent > 1.5f) ? 4 : 2;

        float wsum = 0.f;
#pragma unroll
        for (int r = 0; r < 4; ++r) if (r < kk) wsum += pv[r];

        if (lane == 0) {
            const size_t tt = (size_t)(t0 + i);
#pragma unroll
            for (int r = 0; r < 4; ++r) {
                out[tt * 4 + r]      = (r < kk) ? (float)pi[r] : -1.f;
                out[T4 + tt * 4 + r] = (r < kk) ? pv[r] / wsum : 0.f;
            }
            out[2 * T4 + tt] = (float)kk;
        }
    }
}

extern "C" void kernel_launch(void* const* d_in, const int* in_sizes, int n_in,
                              void* d_out, int out_size, void* d_ws, size_t ws_size,
                              hipStream_t stream) {
    const float* hidden = (const float*)d_in[0];
    const float* weight = (const float*)d_in[1];
    float* out = (float*)d_out;
    const int T = in_sizes[0] / HDIM;              // 16384
    const int blocks = T / (NW * ITOK);            // 512
    hipLaunchKernelGGL(router_lds, dim3(blocks), dim3(256), 0, stream,
                       hidden, weight, out, T);
}

// Round 23
// 231.632 us; speedup vs baseline: 1.8142x; 1.4254x over previous
//
#include <hip/hip_runtime.h>
#include <hip/hip_bf16.h>

#define HDIM 4096
#define EDIM 64
#define ITOK 4          // tokens per wave (16 waves/CU over kernel life)
#define NW   8          // waves per block (512 threads)
#define BH   64         // h-chunk staged in LDS
#define NCH  (HDIM/BH)  // 64 chunks

typedef float f32x4 __attribute__((ext_vector_type(4)));

// Semantics (locked r16): inputs f32-backed bf16; logit = np-einsum-SSE
// 4-chain f32 mul/add (NO FMA), groups of 8 ascending h, (l0+l1)+(l2+l3),
// bf16-round, f32 routing, f32 out [idx 4T | w 4T | k T].
// r23: r19 structure + XOR-swizzled stride-64 LDS -> conflict-free ds_read_b128.
// word (row, c) stored at row*64 + (c ^ (4*(row&7))); 4-word blocks contiguous.
__global__ __launch_bounds__(512) void router_swz(
    const float* __restrict__ hidden,
    const float* __restrict__ weight,
    float* __restrict__ out,
    int T)
{
    __shared__ __align__(16) float wlds[2][EDIM * BH];   // 2 x 16 KB

    const int tid  = threadIdx.x;
    const int lane = tid & 63;
    const int wv   = __builtin_amdgcn_readfirstlane(tid >> 6);
    const int t0   = (blockIdx.x * NW + wv) * ITOK;

    // staging: 512 threads x 8 floats = 64x64 chunk. Row tid>>3, col (tid&7)*8.
    const int srow = tid >> 3;
    const int sq   = (tid & 7) * 8;
    const int sswz = 4 * (srow & 7);          // write swizzle for this row
    const int rswz = 4 * (lane & 7);          // read swizzle for this lane

    float l[ITOK][4];
#pragma unroll
    for (int i = 0; i < ITOK; ++i)
        { l[i][0]=0.f; l[i][1]=0.f; l[i][2]=0.f; l[i][3]=0.f; }

    // ---- prologue: stage chunk 0 ----
    {
        const float* wp = weight + (size_t)srow * HDIM + sq;
        f32x4 v0 = *reinterpret_cast<const f32x4*>(wp);
        f32x4 v1 = *reinterpret_cast<const f32x4*>(wp + 4);
        *reinterpret_cast<f32x4*>(&wlds[0][srow * 64 + ((sq)     ^ sswz)]) = v0;
        *reinterpret_cast<f32x4*>(&wlds[0][srow * 64 + ((sq + 4) ^ sswz)]) = v1;
    }
    __syncthreads();

    for (int c = 0; c < NCH; ++c) {
        const int cur = c & 1;
        if (c + 1 < NCH) {
            const float* wp = weight + (size_t)srow * HDIM + (c + 1) * BH + sq;
            f32x4 v0 = *reinterpret_cast<const f32x4*>(wp);
            f32x4 v1 = *reinterpret_cast<const f32x4*>(wp + 4);
            *reinterpret_cast<f32x4*>(&wlds[cur ^ 1][srow * 64 + ((sq)     ^ sswz)]) = v0;
            *reinterpret_cast<f32x4*>(&wlds[cur ^ 1][srow * 64 + ((sq + 4) ^ sswz)]) = v1;
        }

        const int h0 = c * BH;
#pragma unroll
        for (int g = 0; g < BH / 8; ++g) {
            // conflict-free b128: start bank 8g^rswz spans all 32 banks per 8 lanes
            const f32x4 wa = *reinterpret_cast<const f32x4*>(
                &wlds[cur][lane * 64 + ((g * 8)     ^ rswz)]);
            const f32x4 wb = *reinterpret_cast<const f32x4*>(
                &wlds[cur][lane * 64 + ((g * 8 + 4) ^ rswz)]);
#pragma unroll
            for (int i = 0; i < ITOK; ++i) {
                const float* hp = hidden + (size_t)(t0 + i) * HDIM + h0 + g * 8;
                const f32x4 a0 = *reinterpret_cast<const f32x4*>(hp);
                const f32x4 a1 = *reinterpret_cast<const f32x4*>(hp + 4);
                l[i][0] = __fadd_rn(l[i][0], __fmul_rn(a0.x, wa.x));
                l[i][1] = __fadd_rn(l[i][1], __fmul_rn(a0.y, wa.y));
                l[i][2] = __fadd_rn(l[i][2], __fmul_rn(a0.z, wa.z));
                l[i][3] = __fadd_rn(l[i][3], __fmul_rn(a0.w, wa.w));
                l[i][0] = __fadd_rn(l[i][0], __fmul_rn(a1.x, wb.x));
                l[i][1] = __fadd_rn(l[i][1], __fmul_rn(a1.y, wb.y));
                l[i][2] = __fadd_rn(l[i][2], __fmul_rn(a1.z, wb.z));
                l[i][3] = __fadd_rn(l[i][3], __fmul_rn(a1.w, wb.w));
            }
        }
        __syncthreads();
    }

    const size_t T4 = (size_t)T * 4;

#pragma unroll 1
    for (int i = 0; i < ITOK; ++i) {
        const float acc = __fadd_rn(__fadd_rn(l[i][0], l[i][1]),
                                    __fadd_rn(l[i][2], l[i][3]));
        const float lv = __bfloat162float(__float2bfloat16(acc));

        float mx = lv;
#pragma unroll
        for (int d = 1; d < 64; d <<= 1) mx = fmaxf(mx, __shfl_xor(mx, d));
        const float ev = expf(lv - mx);
        float s = ev;
#pragma unroll
        for (int d = 1; d < 64; d <<= 1) s += __shfl_xor(s, d);
        const float p = ev / s;

        float ent = p * logf(p + 1e-9f);
#pragma unroll
        for (int d = 1; d < 64; d <<= 1) ent += __shfl_xor(ent, d);
        const float Hent = -ent;

        float pv[4]; int pi[4];
        float cand = p;
#pragma unroll
        for (int r = 0; r < 4; ++r) {
            float bv = cand; int bi = lane;
#pragma unroll
            for (int d = 1; d < 64; d <<= 1) {
                float ov = __shfl_xor(bv, d);
                int   oi = __shfl_xor(bi, d);
                if (ov > bv || (ov == bv && oi < bi)) { bv = ov; bi = oi; }
            }
            pv[r] = bv; pi[r] = bi;
            if (lane == bi) cand = -1.f;
        }

        const int kk = (Hent < 0.3f) ? 1 : (Hent > 1.5f) ? 4 : 2;

        float wsum = 0.f;
#pragma unroll
        for (int r = 0; r < 4; ++r) if (r < kk) wsum += pv[r];

        if (lane == 0) {
            const size_t tt = (size_t)(t0 + i);
#pragma unroll
            for (int r = 0; r < 4; ++r) {
                out[tt * 4 + r]      = (r < kk) ? (float)pi[r] : -1.f;
                out[T4 + tt * 4 + r] = (r < kk) ? pv[r] / wsum : 0.f;
            }
            out[2 * T4 + tt] = (float)kk;
        }
    }
}

extern "C" void kernel_launch(void* const* d_in, const int* in_sizes, int n_in,
                              void* d_out, int out_size, void* d_ws, size_t ws_size,
                              hipStream_t stream) {
    const float* hidden = (const float*)d_in[0];
    const float* weight = (const float*)d_in[1];
    float* out = (float*)d_out;
    const int T = in_sizes[0] / HDIM;              // 16384
    const int blocks = T / (NW * ITOK);            // 512
    hipLaunchKernelGGL(router_swz, dim3(blocks), dim3(512), 0, stream,
                       hidden, weight, out, T);
}